// Round 4
// baseline (164.923 us; speedup 1.0000x reference)
//
#include <hip/hip_runtime.h>

typedef _Float16 half8 __attribute__((ext_vector_type(8)));
typedef _Float16 half4 __attribute__((ext_vector_type(4)));
typedef float f32x4 __attribute__((ext_vector_type(4)));

#define NHEAD 12
#define HDIM  64
#define SEQ   1024
#define CDIM  768
#define O3    2304
#define MTOK  8192

__device__ __forceinline__ void load_lds16(const void* g, void* l) {
  __builtin_amdgcn_global_load_lds(
      (const __attribute__((address_space(1))) unsigned int*)g,
      (__attribute__((address_space(3))) unsigned int*)l, 16, 0, 0);
}

// ---------------- cast fp32 -> fp16 (4 elems/thread, vectorized) ----------------
__global__ __launch_bounds__(256) void cast_f2h(const float* __restrict__ in,
                                                _Float16* __restrict__ out) {
  size_t i = ((size_t)blockIdx.x * 256 + threadIdx.x) * 4;
  float4 v = *reinterpret_cast<const float4*>(in + i);
  half4 h;
  h[0] = (_Float16)v.x; h[1] = (_Float16)v.y; h[2] = (_Float16)v.z; h[3] = (_Float16)v.w;
  *reinterpret_cast<half4*>(out + i) = h;
}

// ---------------- QKV GEMM: x_h[8192,768] @ w_qkv_h[2304,768]^T ----------------
// Double-buffered LDS (T3 minimum 2-phase), XCD-swizzled block id (T1).
__global__ __launch_bounds__(256) void qkv_gemm(const _Float16* __restrict__ A,
                                                const _Float16* __restrict__ Bw,
                                                _Float16* __restrict__ Qh,
                                                _Float16* __restrict__ Kh,
                                                _Float16* __restrict__ VT) {
  __shared__ _Float16 As[2][128 * 32];
  __shared__ _Float16 Bs[2][128 * 32];
  const int tid  = threadIdx.x;
  const int lane = tid & 63;
  const int wv   = tid >> 6;
  const int wm   = wv >> 1;
  const int wn   = wv & 1;
  const int fr   = lane & 15;
  const int kg   = lane >> 4;

  // XCD swizzle: nwg = 18*64 = 1152, 1152 % 8 == 0 -> simple variant bijective
  const int lin = blockIdx.y * gridDim.x + blockIdx.x;
  const int cpx = (gridDim.x * gridDim.y) >> 3;
  const int swz = (lin & 7) * cpx + (lin >> 3);
  const int m0  = (swz / 18) * 128;
  const int n0  = (swz % 18) * 128;

  f32x4 acc[4][4];
#pragma unroll
  for (int i = 0; i < 4; ++i)
#pragma unroll
    for (int j = 0; j < 4; ++j) acc[i][j] = (f32x4){0.f, 0.f, 0.f, 0.f};

  auto stage = [&](int buf, int kt) {
#pragma unroll
    for (int r = 0; r < 2; ++r) {
      const int c = r * 256 + tid;
      const int row = c >> 2, cc = c & 3;
      load_lds16(A + (size_t)(m0 + row) * CDIM + kt + ((cc ^ (row & 3)) * 8),
                 &As[buf][c * 8]);
    }
#pragma unroll
    for (int r = 0; r < 2; ++r) {
      const int c = r * 256 + tid;
      const int row = c >> 2, cc = c & 3;
      load_lds16(Bw + (size_t)(n0 + row) * CDIM + kt + ((cc ^ (row & 3)) * 8),
                 &Bs[buf][c * 8]);
    }
  };

  int cur = 0;
  stage(0, 0);
  __syncthreads();

  for (int it = 0; it < 24; ++it) {
    if (it + 1 < 24) stage(cur ^ 1, (it + 1) * 32);   // prefetch overlaps compute
    half8 a[4], b[4];
#pragma unroll
    for (int i = 0; i < 4; ++i) {
      const int row = wm * 64 + i * 16 + fr;
      a[i] = *reinterpret_cast<half8*>(&As[cur][row * 32 + ((kg ^ (row & 3)) * 8)]);
    }
#pragma unroll
    for (int j = 0; j < 4; ++j) {
      const int row = wn * 64 + j * 16 + fr;
      b[j] = *reinterpret_cast<half8*>(&Bs[cur][row * 32 + ((kg ^ (row & 3)) * 8)]);
    }
#pragma unroll
    for (int i = 0; i < 4; ++i)
#pragma unroll
      for (int j = 0; j < 4; ++j)
        acc[i][j] = __builtin_amdgcn_mfma_f32_16x16x32_f16(a[i], b[j], acc[i][j], 0, 0, 0);
    if (it + 1 < 24) {
      __syncthreads();   // compiler emits vmcnt(0) drain here; buf cur^1 ready
      cur ^= 1;
    }
  }

  // epilogue: t uniform per block (128-col tile never straddles 768-boundary)
  const int t     = n0 / CDIM;
  const int hbase = n0 - t * CDIM;
#pragma unroll
  for (int i = 0; i < 4; ++i) {
    const int mrow = m0 + wm * 64 + i * 16 + kg * 4;
#pragma unroll
    for (int j = 0; j < 4; ++j) {
      const int hd = hbase + wn * 64 + j * 16 + fr;
      const int h  = hd >> 6, d = hd & 63;
#pragma unroll
      for (int r = 0; r < 4; ++r) {
        const int m  = mrow + r;
        const int bb = m >> 10, nn = m & 1023;
        const float v = acc[i][j][r];
        if (t == 0)
          Qh[(((size_t)(bb * NHEAD + h)) << 16) + (nn << 6) + d] = (_Float16)(v * 0.125f);
        else if (t == 1)
          Kh[(((size_t)(bb * NHEAD + h)) << 16) + (nn << 6) + d] = (_Float16)v;
        else
          VT[(((size_t)(bb * NHEAD + h)) << 16) + (d << 10) + nn] = (_Float16)v;
      }
    }
  }
}

// ---------------- flash attention, swapped-QK^T in-register softmax ----------------
// block = (bh, 64-row q-tile), 4 waves x 16 q-rows. grid (96,16).
__global__ __launch_bounds__(256) void attn_kernel(const _Float16* __restrict__ Qh,
                                                   const _Float16* __restrict__ Kh,
                                                   const _Float16* __restrict__ VT,
                                                   _Float16* __restrict__ AO) {
  __shared__ _Float16 Ks[64 * 64];        // [key][d], XOR-swizzled 16B chunks
  __shared__ _Float16 Vs[64 * 64];        // [d][key], XOR-swizzled 16B chunks
  __shared__ _Float16 Ps[4 * 16 * 64];    // per-wave packed P [16 q][64 key], slot-swizzled
  const int tid  = threadIdx.x;
  const int lane = tid & 63;
  const int w    = tid >> 6;
  const int fr   = lane & 15;
  const int kg   = lane >> 4;
  const int kh   = kg * 8;
  const int bh   = blockIdx.x;            // 0..95
  const int qt   = blockIdx.y;            // 0..15
  const int q0   = qt * 64 + w * 16;      // wave's first q-row
  const size_t qkbase = (size_t)bh * SEQ * HDIM;
  char* const psw = (char*)&Ps[w * 16 * 64];

  half8 qb[2];
#pragma unroll
  for (int ks = 0; ks < 2; ++ks)
    qb[ks] = *reinterpret_cast<const half8*>(
        &Qh[qkbase + (size_t)(q0 + fr) * HDIM + ks * 32 + kh]);

  f32x4 O[4];
  float mrun = -__builtin_inff();
  float lrun = 0.f;
#pragma unroll
  for (int fd = 0; fd < 4; ++fd) O[fd] = (f32x4){0.f, 0.f, 0.f, 0.f};

  for (int kt = 0; kt < SEQ; kt += 64) {
    __syncthreads();
#pragma unroll
    for (int r = 0; r < 2; ++r) {
      const int c = r * 256 + tid;
      const int row = c >> 3, cc = c & 7;
      load_lds16(&Kh[qkbase + (size_t)(kt + row) * HDIM + ((cc ^ (row & 7)) * 8)], &Ks[c * 8]);
    }
#pragma unroll
    for (int r = 0; r < 2; ++r) {
      const int c = r * 256 + tid;
      const int row = c >> 3, cc = c & 7;
      load_lds16(&VT[(size_t)bh * HDIM * SEQ + (size_t)row * SEQ + kt + ((cc ^ (row & 7)) * 8)],
                 &Vs[c * 8]);
    }
    __syncthreads();

    f32x4 st[4];
#pragma unroll
    for (int fc = 0; fc < 4; ++fc) st[fc] = (f32x4){0.f, 0.f, 0.f, 0.f};
#pragma unroll
    for (int ks = 0; ks < 2; ++ks) {
#pragma unroll
      for (int fc = 0; fc < 4; ++fc) {
        const int row = fc * 16 + fr;
        const int colh = ks * 32 + kh;
        half8 ka = *reinterpret_cast<half8*>(&Ks[row * 64 + (((colh >> 3) ^ (row & 7)) << 3)]);
        st[fc] = __builtin_amdgcn_mfma_f32_16x16x32_f16(ka, qb[ks], st[fc], 0, 0, 0);
      }
    }

    float mx = st[0][0];
#pragma unroll
    for (int fc = 0; fc < 4; ++fc)
#pragma unroll
      for (int r = 0; r < 4; ++r) mx = fmaxf(mx, st[fc][r]);
    mx = fmaxf(mx, __shfl_xor(mx, 16));
    mx = fmaxf(mx, __shfl_xor(mx, 32));
    const float mnew = fmaxf(mrun, mx);
    const float corr = __expf(mrun - mnew);
    mrun = mnew;
    float rs = 0.f;
#pragma unroll
    for (int fc = 0; fc < 4; ++fc)
#pragma unroll
      for (int r = 0; r < 4; ++r) {
        const float p = __expf(st[fc][r] - mnew);
        st[fc][r] = p;
        rs += p;
      }
    rs += __shfl_xor(rs, 16);
    rs += __shfl_xor(rs, 32);
    lrun = lrun * corr + rs;

#pragma unroll
    for (int r = 0; r < 4; ++r) {
      const float c4 = __shfl(corr, kg * 4 + r);
#pragma unroll
      for (int fd = 0; fd < 4; ++fd) O[fd][r] *= c4;
    }

#pragma unroll
    for (int fc = 0; fc < 4; ++fc) {
      half4 pk;
      pk[0] = (_Float16)st[fc][0];
      pk[1] = (_Float16)st[fc][1];
      pk[2] = (_Float16)st[fc][2];
      pk[3] = (_Float16)st[fc][3];
      const int slot = (fc * 2 + (kg >> 1)) ^ (fr & 7);
      *reinterpret_cast<half4*>(psw + fr * 128 + slot * 16 + (kg & 1) * 8) = pk;
    }

#pragma unroll
    for (int ks = 0; ks < 2; ++ks) {
      const int rslot = (ks * 4 + kg) ^ (fr & 7);
      half8 pa = *reinterpret_cast<half8*>(psw + fr * 128 + rslot * 16);
#pragma unroll
      for (int fd = 0; fd < 4; ++fd) {
        const int row = fd * 16 + fr;
        const int colh = ks * 32 + kh;
        half8 vb = *reinterpret_cast<half8*>(&Vs[row * 64 + (((colh >> 3) ^ (row & 7)) << 3)]);
        O[fd] = __builtin_amdgcn_mfma_f32_16x16x32_f16(pa, vb, O[fd], 0, 0, 0);
      }
    }
  }

  const int b = bh / NHEAD, h = bh % NHEAD;
  const float linv = 1.0f / lrun;
#pragma unroll
  for (int r = 0; r < 4; ++r) {
    const float lq = __shfl(linv, kg * 4 + r);
    const int n = q0 + kg * 4 + r;
#pragma unroll
    for (int fd = 0; fd < 4; ++fd)
      AO[((size_t)b * SEQ + n) * CDIM + h * HDIM + fd * 16 + fr] =
          (_Float16)(O[fd][r] * lq);
  }
}

// ---------------- proj GEMM: AO_h[8192,768] @ w_proj_h[768,768]^T + bias -> fp32 ----------------
__global__ __launch_bounds__(256) void proj_gemm(const _Float16* __restrict__ A,
                                                 const _Float16* __restrict__ Bw,
                                                 const float* __restrict__ bias,
                                                 float* __restrict__ Out) {
  __shared__ _Float16 As[2][128 * 32];
  __shared__ _Float16 Bs[2][128 * 32];
  const int tid  = threadIdx.x;
  const int lane = tid & 63;
  const int wv   = tid >> 6;
  const int wm   = wv >> 1;
  const int wn   = wv & 1;
  const int fr   = lane & 15;
  const int kg   = lane >> 4;

  // XCD swizzle: nwg = 6*64 = 384, 384 % 8 == 0
  const int lin = blockIdx.y * gridDim.x + blockIdx.x;
  const int cpx = (gridDim.x * gridDim.y) >> 3;
  const int swz = (lin & 7) * cpx + (lin >> 3);
  const int m0  = (swz / 6) * 128;
  const int n0  = (swz % 6) * 128;

  f32x4 acc[4][4];
#pragma unroll
  for (int i = 0; i < 4; ++i)
#pragma unroll
    for (int j = 0; j < 4; ++j) acc[i][j] = (f32x4){0.f, 0.f, 0.f, 0.f};

  auto stage = [&](int buf, int kt) {
#pragma unroll
    for (int r = 0; r < 2; ++r) {
      const int c = r * 256 + tid;
      const int row = c >> 2, cc = c & 3;
      load_lds16(A + (size_t)(m0 + row) * CDIM + kt + ((cc ^ (row & 3)) * 8),
                 &As[buf][c * 8]);
    }
#pragma unroll
    for (int r = 0; r < 2; ++r) {
      const int c = r * 256 + tid;
      const int row = c >> 2, cc = c & 3;
      load_lds16(Bw + (size_t)(n0 + row) * CDIM + kt + ((cc ^ (row & 3)) * 8),
                 &Bs[buf][c * 8]);
    }
  };

  int cur = 0;
  stage(0, 0);
  __syncthreads();

  for (int it = 0; it < 24; ++it) {
    if (it + 1 < 24) stage(cur ^ 1, (it + 1) * 32);
    half8 a[4], b[4];
#pragma unroll
    for (int i = 0; i < 4; ++i) {
      const int row = wm * 64 + i * 16 + fr;
      a[i] = *reinterpret_cast<half8*>(&As[cur][row * 32 + ((kg ^ (row & 3)) * 8)]);
    }
#pragma unroll
    for (int j = 0; j < 4; ++j) {
      const int row = wn * 64 + j * 16 + fr;
      b[j] = *reinterpret_cast<half8*>(&Bs[cur][row * 32 + ((kg ^ (row & 3)) * 8)]);
    }
#pragma unroll
    for (int i = 0; i < 4; ++i)
#pragma unroll
      for (int j = 0; j < 4; ++j)
        acc[i][j] = __builtin_amdgcn_mfma_f32_16x16x32_f16(a[i], b[j], acc[i][j], 0, 0, 0);
    if (it + 1 < 24) {
      __syncthreads();
      cur ^= 1;
    }
  }

#pragma unroll
  for (int i = 0; i < 4; ++i) {
    const int mrow = m0 + wm * 64 + i * 16 + kg * 4;
#pragma unroll
    for (int j = 0; j < 4; ++j) {
      const int ocol = n0 + wn * 64 + j * 16 + fr;
      const float bv = bias[ocol];
#pragma unroll
      for (int r = 0; r < 4; ++r)
        Out[(size_t)(mrow + r) * CDIM + ocol] = acc[i][j][r] + bv;
    }
  }
}

extern "C" void kernel_launch(void* const* d_in, const int* in_sizes, int n_in,
                              void* d_out, int out_size, void* d_ws, size_t ws_size,
                              hipStream_t stream) {
  const float* x     = (const float*)d_in[0];
  const float* wqkv  = (const float*)d_in[1];
  const float* wproj = (const float*)d_in[2];
  const float* bproj = (const float*)d_in[3];
  float* out = (float*)d_out;

  char* ws = (char*)d_ws;
  _Float16* x_h     = (_Float16*)(ws);
  _Float16* wqkv_h  = (_Float16*)(ws + 12582912);
  _Float16* wproj_h = (_Float16*)(ws + 16121856);
  _Float16* Qh      = (_Float16*)(ws + 17301504);
  _Float16* Kh      = (_Float16*)(ws + 29884416);
  _Float16* VT      = (_Float16*)(ws + 42467328);
  _Float16* AOh     = (_Float16*)(ws + 55050240);

  cast_f2h<<<6291456 / 1024, 256, 0, stream>>>(x, x_h);
  cast_f2h<<<1769472 / 1024, 256, 0, stream>>>(wqkv, wqkv_h);
  cast_f2h<<<589824 / 1024, 256, 0, stream>>>(wproj, wproj_h);

  qkv_gemm<<<dim3(O3 / 128, MTOK / 128), 256, 0, stream>>>(x_h, wqkv_h, Qh, Kh, VT);
  attn_kernel<<<dim3(96, 16), 256, 0, stream>>>(Qh, Kh, VT, AOh);
  proj_gemm<<<dim3(CDIM / 128, MTOK / 128), 256, 0, stream>>>(AOh, wproj_h, bproj, out);
}

// Round 5
// 144.049 us; speedup vs baseline: 1.1449x; 1.1449x over previous
//
#include <hip/hip_runtime.h>

typedef _Float16 half8 __attribute__((ext_vector_type(8)));
typedef _Float16 half4 __attribute__((ext_vector_type(4)));
typedef float f32x4 __attribute__((ext_vector_type(4)));

#define NHEAD 12
#define HDIM  64
#define SEQ   1024
#define CDIM  768
#define O3    2304
#define MTOK  8192

__device__ __forceinline__ void load_lds16(const void* g, void* l) {
  __builtin_amdgcn_global_load_lds(
      (const __attribute__((address_space(1))) unsigned int*)g,
      (__attribute__((address_space(3))) unsigned int*)l, 16, 0, 0);
}

// ---------------- cast fp32 -> fp16 (4 elems/thread, vectorized) ----------------
__global__ __launch_bounds__(256) void cast_f2h(const float* __restrict__ in,
                                                _Float16* __restrict__ out) {
  size_t i = ((size_t)blockIdx.x * 256 + threadIdx.x) * 4;
  float4 v = *reinterpret_cast<const float4*>(in + i);
  half4 h;
  h[0] = (_Float16)v.x; h[1] = (_Float16)v.y; h[2] = (_Float16)v.z; h[3] = (_Float16)v.w;
  *reinterpret_cast<half4*>(out + i) = h;
}

// ---------------- QKV GEMM: 128x128 tile, BK=64, static double-buffer ----------------
__global__ __launch_bounds__(256) void qkv_gemm(const _Float16* __restrict__ A,
                                                const _Float16* __restrict__ Bw,
                                                _Float16* __restrict__ Qh,
                                                _Float16* __restrict__ Kh,
                                                _Float16* __restrict__ VT) {
  __shared__ _Float16 As0[128 * 64], Bs0[128 * 64];
  __shared__ _Float16 As1[128 * 64], Bs1[128 * 64];
  const int tid  = threadIdx.x;
  const int lane = tid & 63;
  const int wv   = tid >> 6;
  const int wm   = wv >> 1;
  const int wn   = wv & 1;
  const int fr   = lane & 15;
  const int kg   = lane >> 4;

  // XCD swizzle: nwg = 1152, %8==0 -> bijective
  const int lin = blockIdx.y * gridDim.x + blockIdx.x;
  const int cpx = (gridDim.x * gridDim.y) >> 3;
  const int swz = (lin & 7) * cpx + (lin >> 3);
  const int m0  = (swz / 18) * 128;
  const int n0  = (swz % 18) * 128;

  f32x4 acc[4][4];
#pragma unroll
  for (int i = 0; i < 4; ++i)
#pragma unroll
    for (int j = 0; j < 4; ++j) acc[i][j] = (f32x4){0.f, 0.f, 0.f, 0.f};

  // stage one 128x64 tile pair; rows = 128B, 8 chunks of 16B, source XOR-preswizzled
  auto stage = [&](_Float16* Ad, _Float16* Bd, int kt) {
#pragma unroll
    for (int r = 0; r < 4; ++r) {
      const int c = r * 256 + tid;
      const int row = c >> 3, cc = c & 7;
      load_lds16(A + (size_t)(m0 + row) * CDIM + kt + ((cc ^ (row & 7)) * 8), Ad + c * 8);
    }
#pragma unroll
    for (int r = 0; r < 4; ++r) {
      const int c = r * 256 + tid;
      const int row = c >> 3, cc = c & 7;
      load_lds16(Bw + (size_t)(n0 + row) * CDIM + kt + ((cc ^ (row & 7)) * 8), Bd + c * 8);
    }
  };

  auto compute = [&](const _Float16* As, const _Float16* Bs) {
#pragma unroll
    for (int kk = 0; kk < 2; ++kk) {
      half8 a[4], b[4];
#pragma unroll
      for (int i = 0; i < 4; ++i) {
        const int row = wm * 64 + i * 16 + fr;
        a[i] = *reinterpret_cast<const half8*>(
            &As[row * 64 + (((kk * 4 + kg) ^ (row & 7)) * 8)]);
      }
#pragma unroll
      for (int j = 0; j < 4; ++j) {
        const int row = wn * 64 + j * 16 + fr;
        b[j] = *reinterpret_cast<const half8*>(
            &Bs[row * 64 + (((kk * 4 + kg) ^ (row & 7)) * 8)]);
      }
#pragma unroll
      for (int i = 0; i < 4; ++i)
#pragma unroll
        for (int j = 0; j < 4; ++j)
          acc[i][j] = __builtin_amdgcn_mfma_f32_16x16x32_f16(a[i], b[j], acc[i][j], 0, 0, 0);
    }
  };

  stage(As0, Bs0, 0);
  __syncthreads();
  for (int it = 0; it < 6; ++it) {
    const int kt = it * 128;
    stage(As1, Bs1, kt + 64);          // full compute-phase cover before use
    compute(As0, Bs0);
    __syncthreads();
    if (kt + 128 < CDIM) stage(As0, Bs0, kt + 128);
    compute(As1, Bs1);
    __syncthreads();
  }

  // epilogue: t uniform per block (128-col tile never straddles 768-boundary)
  const int t     = n0 / CDIM;
  const int hbase = n0 - t * CDIM;
#pragma unroll
  for (int i = 0; i < 4; ++i) {
    const int mrow = m0 + wm * 64 + i * 16 + kg * 4;
#pragma unroll
    for (int j = 0; j < 4; ++j) {
      const int hd = hbase + wn * 64 + j * 16 + fr;
      const int h  = hd >> 6, d = hd & 63;
#pragma unroll
      for (int r = 0; r < 4; ++r) {
        const int m  = mrow + r;
        const int bb = m >> 10, nn = m & 1023;
        const float v = acc[i][j][r];
        if (t == 0)
          Qh[(((size_t)(bb * NHEAD + h)) << 16) + (nn << 6) + d] = (_Float16)(v * 0.125f);
        else if (t == 1)
          Kh[(((size_t)(bb * NHEAD + h)) << 16) + (nn << 6) + d] = (_Float16)v;
        else
          VT[(((size_t)(bb * NHEAD + h)) << 16) + (d << 10) + nn] = (_Float16)v;
      }
    }
  }
}

// ---------------- flash attention, swapped-QK^T, K/V double-buffered ----------------
// block = (bh, 64-row q-tile), 4 waves x 16 q-rows. grid (96,16).
__global__ __launch_bounds__(256) void attn_kernel(const _Float16* __restrict__ Qh,
                                                   const _Float16* __restrict__ Kh,
                                                   const _Float16* __restrict__ VT,
                                                   _Float16* __restrict__ AO) {
  __shared__ _Float16 Ks0[64 * 64], Vs0[64 * 64];
  __shared__ _Float16 Ks1[64 * 64], Vs1[64 * 64];
  __shared__ _Float16 Ps[4 * 16 * 64];    // per-wave packed P, slot-swizzled
  const int tid  = threadIdx.x;
  const int lane = tid & 63;
  const int w    = tid >> 6;
  const int fr   = lane & 15;
  const int kg   = lane >> 4;
  const int kh   = kg * 8;
  const int bh   = blockIdx.x;
  const int qt   = blockIdx.y;
  const int q0   = qt * 64 + w * 16;
  const size_t qkbase = (size_t)bh * SEQ * HDIM;
  char* const psw = (char*)&Ps[w * 16 * 64];

  half8 qb[2];
#pragma unroll
  for (int ks = 0; ks < 2; ++ks)
    qb[ks] = *reinterpret_cast<const half8*>(
        &Qh[qkbase + (size_t)(q0 + fr) * HDIM + ks * 32 + kh]);

  f32x4 O[4];
  float mrun = -__builtin_inff();
  float lrun = 0.f;
#pragma unroll
  for (int fd = 0; fd < 4; ++fd) O[fd] = (f32x4){0.f, 0.f, 0.f, 0.f};

  auto stageKV = [&](_Float16* Kd, _Float16* Vd, int kt) {
#pragma unroll
    for (int r = 0; r < 2; ++r) {
      const int c = r * 256 + tid;
      const int row = c >> 3, cc = c & 7;
      load_lds16(&Kh[qkbase + (size_t)(kt + row) * HDIM + ((cc ^ (row & 7)) * 8)], Kd + c * 8);
    }
#pragma unroll
    for (int r = 0; r < 2; ++r) {
      const int c = r * 256 + tid;
      const int row = c >> 3, cc = c & 7;
      load_lds16(&VT[(size_t)bh * HDIM * SEQ + (size_t)row * SEQ + kt + ((cc ^ (row & 7)) * 8)],
                 Vd + c * 8);
    }
  };

  auto computeKV = [&](const _Float16* Ksrc, const _Float16* Vsrc) {
    f32x4 st[4];
#pragma unroll
    for (int fc = 0; fc < 4; ++fc) st[fc] = (f32x4){0.f, 0.f, 0.f, 0.f};
#pragma unroll
    for (int ks = 0; ks < 2; ++ks) {
#pragma unroll
      for (int fc = 0; fc < 4; ++fc) {
        const int row = fc * 16 + fr;
        const int colh = ks * 32 + kh;
        half8 ka = *reinterpret_cast<const half8*>(
            &Ksrc[row * 64 + (((colh >> 3) ^ (row & 7)) << 3)]);
        st[fc] = __builtin_amdgcn_mfma_f32_16x16x32_f16(ka, qb[ks], st[fc], 0, 0, 0);
      }
    }

    float mx = st[0][0];
#pragma unroll
    for (int fc = 0; fc < 4; ++fc)
#pragma unroll
      for (int r = 0; r < 4; ++r) mx = fmaxf(mx, st[fc][r]);
    mx = fmaxf(mx, __shfl_xor(mx, 16));
    mx = fmaxf(mx, __shfl_xor(mx, 32));
    const float mnew = fmaxf(mrun, mx);
    const float corr = __expf(mrun - mnew);
    mrun = mnew;
    float rs = 0.f;
#pragma unroll
    for (int fc = 0; fc < 4; ++fc)
#pragma unroll
      for (int r = 0; r < 4; ++r) {
        const float p = __expf(st[fc][r] - mnew);
        st[fc][r] = p;
        rs += p;
      }
    rs += __shfl_xor(rs, 16);
    rs += __shfl_xor(rs, 32);
    lrun = lrun * corr + rs;

#pragma unroll
    for (int r = 0; r < 4; ++r) {
      const float c4 = __shfl(corr, kg * 4 + r);
#pragma unroll
      for (int fd = 0; fd < 4; ++fd) O[fd][r] *= c4;
    }

#pragma unroll
    for (int fc = 0; fc < 4; ++fc) {
      half4 pk;
      pk[0] = (_Float16)st[fc][0];
      pk[1] = (_Float16)st[fc][1];
      pk[2] = (_Float16)st[fc][2];
      pk[3] = (_Float16)st[fc][3];
      const int slot = (fc * 2 + (kg >> 1)) ^ (fr & 7);
      *reinterpret_cast<half4*>(psw + fr * 128 + slot * 16 + (kg & 1) * 8) = pk;
    }

#pragma unroll
    for (int ks = 0; ks < 2; ++ks) {
      const int rslot = (ks * 4 + kg) ^ (fr & 7);
      half8 pa = *reinterpret_cast<half8*>(psw + fr * 128 + rslot * 16);
#pragma unroll
      for (int fd = 0; fd < 4; ++fd) {
        const int row = fd * 16 + fr;
        const int colh = ks * 32 + kh;
        half8 vb = *reinterpret_cast<const half8*>(
            &Vsrc[row * 64 + (((colh >> 3) ^ (row & 7)) << 3)]);
        O[fd] = __builtin_amdgcn_mfma_f32_16x16x32_f16(pa, vb, O[fd], 0, 0, 0);
      }
    }
  };

  stageKV(Ks0, Vs0, 0);
  __syncthreads();
  for (int it = 0; it < 8; ++it) {
    const int kt = it * 128;
    stageKV(Ks1, Vs1, kt + 64);        // cover = full compute phase
    computeKV(Ks0, Vs0);
    __syncthreads();
    if (kt + 128 < SEQ) stageKV(Ks0, Vs0, kt + 128);
    computeKV(Ks1, Vs1);
    __syncthreads();
  }

  const int b = bh / NHEAD, h = bh % NHEAD;
  const float linv = 1.0f / lrun;
#pragma unroll
  for (int r = 0; r < 4; ++r) {
    const float lq = __shfl(linv, kg * 4 + r);
    const int n = q0 + kg * 4 + r;
#pragma unroll
    for (int fd = 0; fd < 4; ++fd)
      AO[((size_t)b * SEQ + n) * CDIM + h * HDIM + fd * 16 + fr] =
          (_Float16)(O[fd][r] * lq);
  }
}

// ---------------- proj GEMM: 128x128, BK=64, static double-buffer ----------------
__global__ __launch_bounds__(256) void proj_gemm(const _Float16* __restrict__ A,
                                                 const _Float16* __restrict__ Bw,
                                                 const float* __restrict__ bias,
                                                 float* __restrict__ Out) {
  __shared__ _Float16 As0[128 * 64], Bs0[128 * 64];
  __shared__ _Float16 As1[128 * 64], Bs1[128 * 64];
  const int tid  = threadIdx.x;
  const int lane = tid & 63;
  const int wv   = tid >> 6;
  const int wm   = wv >> 1;
  const int wn   = wv & 1;
  const int fr   = lane & 15;
  const int kg   = lane >> 4;

  // XCD swizzle: nwg = 384, %8==0
  const int lin = blockIdx.y * gridDim.x + blockIdx.x;
  const int cpx = (gridDim.x * gridDim.y) >> 3;
  const int swz = (lin & 7) * cpx + (lin >> 3);
  const int m0  = (swz / 6) * 128;
  const int n0  = (swz % 6) * 128;

  f32x4 acc[4][4];
#pragma unroll
  for (int i = 0; i < 4; ++i)
#pragma unroll
    for (int j = 0; j < 4; ++j) acc[i][j] = (f32x4){0.f, 0.f, 0.f, 0.f};

  auto stage = [&](_Float16* Ad, _Float16* Bd, int kt) {
#pragma unroll
    for (int r = 0; r < 4; ++r) {
      const int c = r * 256 + tid;
      const int row = c >> 3, cc = c & 7;
      load_lds16(A + (size_t)(m0 + row) * CDIM + kt + ((cc ^ (row & 7)) * 8), Ad + c * 8);
    }
#pragma unroll
    for (int r = 0; r < 4; ++r) {
      const int c = r * 256 + tid;
      const int row = c >> 3, cc = c & 7;
      load_lds16(Bw + (size_t)(n0 + row) * CDIM + kt + ((cc ^ (row & 7)) * 8), Bd + c * 8);
    }
  };

  auto compute = [&](const _Float16* As, const _Float16* Bs) {
#pragma unroll
    for (int kk = 0; kk < 2; ++kk) {
      half8 a[4], b[4];
#pragma unroll
      for (int i = 0; i < 4; ++i) {
        const int row = wm * 64 + i * 16 + fr;
        a[i] = *reinterpret_cast<const half8*>(
            &As[row * 64 + (((kk * 4 + kg) ^ (row & 7)) * 8)]);
      }
#pragma unroll
      for (int j = 0; j < 4; ++j) {
        const int row = wn * 64 + j * 16 + fr;
        b[j] = *reinterpret_cast<const half8*>(
            &Bs[row * 64 + (((kk * 4 + kg) ^ (row & 7)) * 8)]);
      }
#pragma unroll
      for (int i = 0; i < 4; ++i)
#pragma unroll
        for (int j = 0; j < 4; ++j)
          acc[i][j] = __builtin_amdgcn_mfma_f32_16x16x32_f16(a[i], b[j], acc[i][j], 0, 0, 0);
    }
  };

  stage(As0, Bs0, 0);
  __syncthreads();
  for (int it = 0; it < 6; ++it) {
    const int kt = it * 128;
    stage(As1, Bs1, kt + 64);
    compute(As0, Bs0);
    __syncthreads();
    if (kt + 128 < CDIM) stage(As0, Bs0, kt + 128);
    compute(As1, Bs1);
    __syncthreads();
  }

#pragma unroll
  for (int i = 0; i < 4; ++i) {
    const int mrow = m0 + wm * 64 + i * 16 + kg * 4;
#pragma unroll
    for (int j = 0; j < 4; ++j) {
      const int ocol = n0 + wn * 64 + j * 16 + fr;
      const float bv = bias[ocol];
#pragma unroll
      for (int r = 0; r < 4; ++r)
        Out[(size_t)(mrow + r) * CDIM + ocol] = acc[i][j][r] + bv;
    }
  }
}

extern "C" void kernel_launch(void* const* d_in, const int* in_sizes, int n_in,
                              void* d_out, int out_size, void* d_ws, size_t ws_size,
                              hipStream_t stream) {
  const float* x     = (const float*)d_in[0];
  const float* wqkv  = (const float*)d_in[1];
  const float* wproj = (const float*)d_in[2];
  const float* bproj = (const float*)d_in[3];
  float* out = (float*)d_out;

  char* ws = (char*)d_ws;
  _Float16* x_h     = (_Float16*)(ws);
  _Float16* wqkv_h  = (_Float16*)(ws + 12582912);
  _Float16* wproj_h = (_Float16*)(ws + 16121856);
  _Float16* Qh      = (_Float16*)(ws + 17301504);
  _Float16* Kh      = (_Float16*)(ws + 29884416);
  _Float16* VT      = (_Float16*)(ws + 42467328);
  _Float16* AOh     = (_Float16*)(ws + 55050240);

  cast_f2h<<<6291456 / 1024, 256, 0, stream>>>(x, x_h);
  cast_f2h<<<1769472 / 1024, 256, 0, stream>>>(wqkv, wqkv_h);
  cast_f2h<<<589824 / 1024, 256, 0, stream>>>(wproj, wproj_h);

  qkv_gemm<<<dim3(O3 / 128, MTOK / 128), 256, 0, stream>>>(x_h, wqkv_h, Qh, Kh, VT);
  attn_kernel<<<dim3(96, 16), 256, 0, stream>>>(Qh, Kh, VT, AOh);
  proj_gemm<<<dim3(CDIM / 128, MTOK / 128), 256, 0, stream>>>(AOh, wproj_h, bproj, out);
}

// Round 6
// 136.605 us; speedup vs baseline: 1.2073x; 1.0545x over previous
//
#include <hip/hip_runtime.h>

typedef _Float16 half8 __attribute__((ext_vector_type(8)));
typedef _Float16 half4 __attribute__((ext_vector_type(4)));
typedef float f32x4 __attribute__((ext_vector_type(4)));

#define NHEAD 12
#define HDIM  64
#define SEQ   1024
#define CDIM  768
#define O3    2304
#define MTOK  8192

__device__ __forceinline__ void load_lds16(const void* g, void* l) {
  __builtin_amdgcn_global_load_lds(
      (const __attribute__((address_space(1))) unsigned int*)g,
      (__attribute__((address_space(3))) unsigned int*)l, 16, 0, 0);
}

// ---------------- cast fp32 -> fp16 (4 elems/thread, vectorized) ----------------
__global__ __launch_bounds__(256) void cast_f2h(const float* __restrict__ in,
                                                _Float16* __restrict__ out) {
  size_t i = ((size_t)blockIdx.x * 256 + threadIdx.x) * 4;
  float4 v = *reinterpret_cast<const float4*>(in + i);
  half4 h;
  h[0] = (_Float16)v.x; h[1] = (_Float16)v.y; h[2] = (_Float16)v.z; h[3] = (_Float16)v.w;
  *reinterpret_cast<half4*>(out + i) = h;
}

// ---------------- QKV GEMM: 128x128 tile, BK=64, static double-buffer ----------------
// XCD swizzle, m-FASTEST within XCD: x-panels (8 x 192KB) pinned in L2, w streams.
__global__ __launch_bounds__(256) void qkv_gemm(const _Float16* __restrict__ A,
                                                const _Float16* __restrict__ Bw,
                                                _Float16* __restrict__ Qh,
                                                _Float16* __restrict__ Kh,
                                                _Float16* __restrict__ VT) {
  __shared__ _Float16 As0[128 * 64], Bs0[128 * 64];
  __shared__ _Float16 As1[128 * 64], Bs1[128 * 64];
  const int tid  = threadIdx.x;
  const int lane = tid & 63;
  const int wv   = tid >> 6;
  const int wm   = wv >> 1;
  const int wn   = wv & 1;
  const int fr   = lane & 15;
  const int kg   = lane >> 4;

  // nwg = 1152 = 8 XCD * 144; XCD k owns m-panels [8k,8k+8) x all 18 n-panels,
  // traversed m-fastest so the XCD's x rows stay L2-resident.
  const int lin = blockIdx.y * gridDim.x + blockIdx.x;
  const int k   = lin & 7;
  const int j   = lin >> 3;                 // 0..143
  const int n0  = (j >> 3) * 128;           // 18 n-panels
  const int m0  = (k * 8 + (j & 7)) * 128;  // 64 m-panels

  f32x4 acc[4][4];
#pragma unroll
  for (int i = 0; i < 4; ++i)
#pragma unroll
    for (int j2 = 0; j2 < 4; ++j2) acc[i][j2] = (f32x4){0.f, 0.f, 0.f, 0.f};

  auto stage = [&](_Float16* Ad, _Float16* Bd, int kt) {
#pragma unroll
    for (int r = 0; r < 4; ++r) {
      const int c = r * 256 + tid;
      const int row = c >> 3, cc = c & 7;
      load_lds16(A + (size_t)(m0 + row) * CDIM + kt + ((cc ^ (row & 7)) * 8), Ad + c * 8);
    }
#pragma unroll
    for (int r = 0; r < 4; ++r) {
      const int c = r * 256 + tid;
      const int row = c >> 3, cc = c & 7;
      load_lds16(Bw + (size_t)(n0 + row) * CDIM + kt + ((cc ^ (row & 7)) * 8), Bd + c * 8);
    }
  };

  auto compute = [&](const _Float16* As, const _Float16* Bs) {
#pragma unroll
    for (int kk = 0; kk < 2; ++kk) {
      half8 a[4], b[4];
#pragma unroll
      for (int i = 0; i < 4; ++i) {
        const int row = wm * 64 + i * 16 + fr;
        a[i] = *reinterpret_cast<const half8*>(
            &As[row * 64 + (((kk * 4 + kg) ^ (row & 7)) * 8)]);
      }
#pragma unroll
      for (int j2 = 0; j2 < 4; ++j2) {
        const int row = wn * 64 + j2 * 16 + fr;
        b[j2] = *reinterpret_cast<const half8*>(
            &Bs[row * 64 + (((kk * 4 + kg) ^ (row & 7)) * 8)]);
      }
#pragma unroll
      for (int i = 0; i < 4; ++i)
#pragma unroll
        for (int j2 = 0; j2 < 4; ++j2)
          acc[i][j2] = __builtin_amdgcn_mfma_f32_16x16x32_f16(a[i], b[j2], acc[i][j2], 0, 0, 0);
    }
  };

  stage(As0, Bs0, 0);
  __syncthreads();
  for (int it = 0; it < 6; ++it) {
    const int kt = it * 128;
    stage(As1, Bs1, kt + 64);
    compute(As0, Bs0);
    __syncthreads();
    if (kt + 128 < CDIM) stage(As0, Bs0, kt + 128);
    compute(As1, Bs1);
    __syncthreads();
  }

  // epilogue; Q prescaled by 0.125*log2(e) so attention can use exp2 directly
  const float QSCALE = 0.125f * 1.44269504088896f;
  const int t     = n0 / CDIM;
  const int hbase = n0 - t * CDIM;
#pragma unroll
  for (int i = 0; i < 4; ++i) {
    const int mrow = m0 + wm * 64 + i * 16 + kg * 4;
#pragma unroll
    for (int j2 = 0; j2 < 4; ++j2) {
      const int hd = hbase + wn * 64 + j2 * 16 + fr;
      const int h  = hd >> 6, d = hd & 63;
#pragma unroll
      for (int r = 0; r < 4; ++r) {
        const int m  = mrow + r;
        const int bb = m >> 10, nn = m & 1023;
        const float v = acc[i][j2][r];
        if (t == 0)
          Qh[(((size_t)(bb * NHEAD + h)) << 16) + (nn << 6) + d] = (_Float16)(v * QSCALE);
        else if (t == 1)
          Kh[(((size_t)(bb * NHEAD + h)) << 16) + (nn << 6) + d] = (_Float16)v;
        else
          VT[(((size_t)(bb * NHEAD + h)) << 16) + (d << 10) + nn] = (_Float16)v;
      }
    }
  }
}

// ---------------- flash attention: 8 waves, QBLK=128, exp2 + defer-max ----------------
// block = (bh, 128-row q-tile), 8 waves x 16 q-rows. grid (96,8).
__global__ __launch_bounds__(512) void attn_kernel(const _Float16* __restrict__ Qh,
                                                   const _Float16* __restrict__ Kh,
                                                   const _Float16* __restrict__ VT,
                                                   _Float16* __restrict__ AO) {
  __shared__ _Float16 Ks0[64 * 64], Vs0[64 * 64];
  __shared__ _Float16 Ks1[64 * 64], Vs1[64 * 64];
  __shared__ _Float16 Ps[8 * 16 * 64];    // per-wave packed P, slot-swizzled
  const int tid  = threadIdx.x;
  const int lane = tid & 63;
  const int w    = tid >> 6;              // 0..7
  const int fr   = lane & 15;
  const int kg   = lane >> 4;
  const int kh   = kg * 8;
  const int bh   = blockIdx.x;
  const int qt   = blockIdx.y;            // 0..7
  const int q0   = qt * 128 + w * 16;
  const size_t qkbase = (size_t)bh * SEQ * HDIM;
  char* const psw = (char*)&Ps[w * 16 * 64];

  half8 qb[2];
#pragma unroll
  for (int ks = 0; ks < 2; ++ks)
    qb[ks] = *reinterpret_cast<const half8*>(
        &Qh[qkbase + (size_t)(q0 + fr) * HDIM + ks * 32 + kh]);

  f32x4 O[4];
  float mrun = -__builtin_inff();
  float lrun = 0.f;
#pragma unroll
  for (int fd = 0; fd < 4; ++fd) O[fd] = (f32x4){0.f, 0.f, 0.f, 0.f};

  auto stageKV = [&](_Float16* Kd, _Float16* Vd, int kt) {
    const int c = tid;                    // 512 chunks, one per thread
    const int row = c >> 3, cc = c & 7;
    load_lds16(&Kh[qkbase + (size_t)(kt + row) * HDIM + ((cc ^ (row & 7)) * 8)], Kd + c * 8);
    load_lds16(&VT[(size_t)bh * HDIM * SEQ + (size_t)row * SEQ + kt + ((cc ^ (row & 7)) * 8)],
               Vd + c * 8);
  };

  auto computeKV = [&](const _Float16* Ksrc, const _Float16* Vsrc) {
    f32x4 st[4];
#pragma unroll
    for (int fc = 0; fc < 4; ++fc) st[fc] = (f32x4){0.f, 0.f, 0.f, 0.f};
#pragma unroll
    for (int ks = 0; ks < 2; ++ks) {
#pragma unroll
      for (int fc = 0; fc < 4; ++fc) {
        const int row = fc * 16 + fr;
        const int colh = ks * 32 + kh;
        half8 ka = *reinterpret_cast<const half8*>(
            &Ksrc[row * 64 + (((colh >> 3) ^ (row & 7)) << 3)]);
        st[fc] = __builtin_amdgcn_mfma_f32_16x16x32_f16(ka, qb[ks], st[fc], 0, 0, 0);
      }
    }

    // scores are in log2 domain (Q prescaled by 0.125*log2e)
    float mx = st[0][0];
#pragma unroll
    for (int fc = 0; fc < 4; ++fc)
#pragma unroll
      for (int r = 0; r < 4; ++r) mx = fmaxf(mx, st[fc][r]);
    mx = fmaxf(mx, __shfl_xor(mx, 16));
    mx = fmaxf(mx, __shfl_xor(mx, 32));

    // defer-max (T13): only rescale when some row's max grew by > 8 (log2 units);
    // P bounded by 2^8=256, fp16-safe, relative precision unchanged.
    if (!__all(mx - mrun <= 8.f)) {
      const float mnew = fmaxf(mrun, mx);
      const float corr = exp2f(mrun - mnew);
      mrun = mnew;
      lrun *= corr;
#pragma unroll
      for (int r = 0; r < 4; ++r) {
        const float c4 = __shfl(corr, kg * 4 + r);
#pragma unroll
        for (int fd = 0; fd < 4; ++fd) O[fd][r] *= c4;
      }
    }

    float rs = 0.f;
#pragma unroll
    for (int fc = 0; fc < 4; ++fc)
#pragma unroll
      for (int r = 0; r < 4; ++r) {
        const float p = exp2f(st[fc][r] - mrun);
        st[fc][r] = p;
        rs += p;
      }
    rs += __shfl_xor(rs, 16);
    rs += __shfl_xor(rs, 32);
    lrun += rs;

#pragma unroll
    for (int fc = 0; fc < 4; ++fc) {
      half4 pk;
      pk[0] = (_Float16)st[fc][0];
      pk[1] = (_Float16)st[fc][1];
      pk[2] = (_Float16)st[fc][2];
      pk[3] = (_Float16)st[fc][3];
      const int slot = (fc * 2 + (kg >> 1)) ^ (fr & 7);
      *reinterpret_cast<half4*>(psw + fr * 128 + slot * 16 + (kg & 1) * 8) = pk;
    }

#pragma unroll
    for (int ks = 0; ks < 2; ++ks) {
      const int rslot = (ks * 4 + kg) ^ (fr & 7);
      half8 pa = *reinterpret_cast<half8*>(psw + fr * 128 + rslot * 16);
#pragma unroll
      for (int fd = 0; fd < 4; ++fd) {
        const int row = fd * 16 + fr;
        const int colh = ks * 32 + kh;
        half8 vb = *reinterpret_cast<const half8*>(
            &Vsrc[row * 64 + (((colh >> 3) ^ (row & 7)) << 3)]);
        O[fd] = __builtin_amdgcn_mfma_f32_16x16x32_f16(pa, vb, O[fd], 0, 0, 0);
      }
    }
  };

  stageKV(Ks0, Vs0, 0);
  __syncthreads();
  for (int it = 0; it < 8; ++it) {
    const int kt = it * 128;
    stageKV(Ks1, Vs1, kt + 64);
    computeKV(Ks0, Vs0);
    __syncthreads();
    if (kt + 128 < SEQ) stageKV(Ks0, Vs0, kt + 128);
    computeKV(Ks1, Vs1);
    __syncthreads();
  }

  const int b = bh / NHEAD, h = bh % NHEAD;
  const float linv = 1.0f / lrun;
#pragma unroll
  for (int r = 0; r < 4; ++r) {
    const float lq = __shfl(linv, kg * 4 + r);
    const int n = q0 + kg * 4 + r;
#pragma unroll
    for (int fd = 0; fd < 4; ++fd)
      AO[((size_t)b * SEQ + n) * CDIM + h * HDIM + fd * 16 + fr] =
          (_Float16)(O[fd][r] * lq);
  }
}

// ---------------- proj GEMM: 128x128, BK=64, static double-buffer ----------------
__global__ __launch_bounds__(256) void proj_gemm(const _Float16* __restrict__ A,
                                                 const _Float16* __restrict__ Bw,
                                                 const float* __restrict__ bias,
                                                 float* __restrict__ Out) {
  __shared__ _Float16 As0[128 * 64], Bs0[128 * 64];
  __shared__ _Float16 As1[128 * 64], Bs1[128 * 64];
  const int tid  = threadIdx.x;
  const int lane = tid & 63;
  const int wv   = tid >> 6;
  const int wm   = wv >> 1;
  const int wn   = wv & 1;
  const int fr   = lane & 15;
  const int kg   = lane >> 4;

  // nwg = 384 = 8 * 48; XCD k owns m-panels [8k,8k+8) x 6 n-panels, m-fastest.
  const int lin = blockIdx.y * gridDim.x + blockIdx.x;
  const int k   = lin & 7;
  const int j   = lin >> 3;                 // 0..47
  const int n0  = (j >> 3) * 128;           // 6 n-panels
  const int m0  = (k * 8 + (j & 7)) * 128;  // 64 m-panels

  f32x4 acc[4][4];
#pragma unroll
  for (int i = 0; i < 4; ++i)
#pragma unroll
    for (int j2 = 0; j2 < 4; ++j2) acc[i][j2] = (f32x4){0.f, 0.f, 0.f, 0.f};

  auto stage = [&](_Float16* Ad, _Float16* Bd, int kt) {
#pragma unroll
    for (int r = 0; r < 4; ++r) {
      const int c = r * 256 + tid;
      const int row = c >> 3, cc = c & 7;
      load_lds16(A + (size_t)(m0 + row) * CDIM + kt + ((cc ^ (row & 7)) * 8), Ad + c * 8);
    }
#pragma unroll
    for (int r = 0; r < 4; ++r) {
      const int c = r * 256 + tid;
      const int row = c >> 3, cc = c & 7;
      load_lds16(Bw + (size_t)(n0 + row) * CDIM + kt + ((cc ^ (row & 7)) * 8), Bd + c * 8);
    }
  };

  auto compute = [&](const _Float16* As, const _Float16* Bs) {
#pragma unroll
    for (int kk = 0; kk < 2; ++kk) {
      half8 a[4], b[4];
#pragma unroll
      for (int i = 0; i < 4; ++i) {
        const int row = wm * 64 + i * 16 + fr;
        a[i] = *reinterpret_cast<const half8*>(
            &As[row * 64 + (((kk * 4 + kg) ^ (row & 7)) * 8)]);
      }
#pragma unroll
      for (int j2 = 0; j2 < 4; ++j2) {
        const int row = wn * 64 + j2 * 16 + fr;
        b[j2] = *reinterpret_cast<const half8*>(
            &Bs[row * 64 + (((kk * 4 + kg) ^ (row & 7)) * 8)]);
      }
#pragma unroll
      for (int i = 0; i < 4; ++i)
#pragma unroll
        for (int j2 = 0; j2 < 4; ++j2)
          acc[i][j2] = __builtin_amdgcn_mfma_f32_16x16x32_f16(a[i], b[j2], acc[i][j2], 0, 0, 0);
    }
  };

  stage(As0, Bs0, 0);
  __syncthreads();
  for (int it = 0; it < 6; ++it) {
    const int kt = it * 128;
    stage(As1, Bs1, kt + 64);
    compute(As0, Bs0);
    __syncthreads();
    if (kt + 128 < CDIM) stage(As0, Bs0, kt + 128);
    compute(As1, Bs1);
    __syncthreads();
  }

#pragma unroll
  for (int i = 0; i < 4; ++i) {
    const int mrow = m0 + wm * 64 + i * 16 + kg * 4;
#pragma unroll
    for (int j2 = 0; j2 < 4; ++j2) {
      const int ocol = n0 + wn * 64 + j2 * 16 + fr;
      const float bv = bias[ocol];
#pragma unroll
      for (int r = 0; r < 4; ++r)
        Out[(size_t)(mrow + r) * CDIM + ocol] = acc[i][j2][r] + bv;
    }
  }
}

extern "C" void kernel_launch(void* const* d_in, const int* in_sizes, int n_in,
                              void* d_out, int out_size, void* d_ws, size_t ws_size,
                              hipStream_t stream) {
  const float* x     = (const float*)d_in[0];
  const float* wqkv  = (const float*)d_in[1];
  const float* wproj = (const float*)d_in[2];
  const float* bproj = (const float*)d_in[3];
  float* out = (float*)d_out;

  char* ws = (char*)d_ws;
  _Float16* x_h     = (_Float16*)(ws);
  _Float16* wqkv_h  = (_Float16*)(ws + 12582912);
  _Float16* wproj_h = (_Float16*)(ws + 16121856);
  _Float16* Qh      = (_Float16*)(ws + 17301504);
  _Float16* Kh      = (_Float16*)(ws + 29884416);
  _Float16* VT      = (_Float16*)(ws + 42467328);
  _Float16* AOh     = (_Float16*)(ws + 55050240);

  cast_f2h<<<6291456 / 1024, 256, 0, stream>>>(x, x_h);
  cast_f2h<<<1769472 / 1024, 256, 0, stream>>>(wqkv, wqkv_h);
  cast_f2h<<<589824 / 1024, 256, 0, stream>>>(wproj, wproj_h);

  qkv_gemm<<<dim3(O3 / 128, MTOK / 128), 256, 0, stream>>>(x_h, wqkv_h, Qh, Kh, VT);
  attn_kernel<<<dim3(96, 8), 512, 0, stream>>>(Qh, Kh, VT, AOh);
  proj_gemm<<<dim3(CDIM / 128, MTOK / 128), 256, 0, stream>>>(AOh, wproj_h, bproj, out);
}